// Round 17
// baseline (266.545 us; speedup 1.0000x reference)
//
#include <hip/hip_runtime.h>
#include <hip/hip_bf16.h>
#include <float.h>

#define N_NODES 100000
#define N_EDGES 1600000
#define HIDDEN 64
#define N_GRAPHS 128
#define NEG_SLOPE 0.2f
#define ETOT (N_EDGES + N_NODES)

#define BSHIFT 8
#define NB ((N_NODES + 255) >> BSHIFT)    // 391 buckets of 256 nodes
#define PAIR_CHUNK 4096
#define PAIR_BLOCKS ((N_EDGES + PAIR_CHUNK - 1) / PAIR_CHUNK)  // 391
#define XBIT_BLOCKS ((N_NODES + 255) / 256)                     // 391
#define TBL_BLOCKS (NLVL / 4)                                   // 128

#define NREP 64           // pool accumulator replicas
#define REP_STRIDE 272
#define NLVL 512          // c1 quantization levels (layer-1 table)

__device__ __forceinline__ unsigned short f2bf(float f) {
    unsigned u = __float_as_uint(f);
    unsigned r = (u + 0x7FFFu + ((u >> 16) & 1u)) >> 16;  // RNE
    return (unsigned short)r;
}
__device__ __forceinline__ float blo(unsigned u) { return __uint_as_float(u << 16); }
__device__ __forceinline__ float bhi(unsigned u) { return __uint_as_float(u & 0xFFFF0000u); }
__device__ __forceinline__ int sb0(unsigned u) { return (int)((unsigned)(u << 24)) >> 24; }
__device__ __forceinline__ int sb1(unsigned u) { return (int)((unsigned)(u << 16)) >> 24; }
__device__ __forceinline__ int sb2(unsigned u) { return (int)((unsigned)(u << 8)) >> 24; }
__device__ __forceinline__ int sb3(unsigned u) { return (int)u >> 24; }

// ---------------- fused prep: edge bucket counts | layer-1 table | x bitmask + deg zero ----------------

__global__ __launch_bounds__(256) void k_prep(
    const int* __restrict__ e1, const int* __restrict__ x,
    const float* __restrict__ embed, const float* __restrict__ Ws,
    const float* __restrict__ biases, const float* __restrict__ a_srcs,
    const float* __restrict__ a_dsts, const float* __restrict__ W_out,
    int* __restrict__ blockcnt, float* __restrict__ pool_acc,
    unsigned* __restrict__ xb, int* __restrict__ degg,
    unsigned char* __restrict__ Tq8, float* __restrict__ Tscl,
    float* __restrict__ Ts1s, float* __restrict__ Ts1d,
    float* __restrict__ sparams)
{
    __shared__ int hcnt[NB];
    int t = threadIdx.x, b = blockIdx.x;

    if (b < PAIR_BLOCKS) {
        // ---- bucket counts for chunk b (+ zero pool_acc replicas) ----
        for (int i = t; i < NB; i += 256) hcnt[i] = 0;
        if (b < NREP && t < 2 * N_GRAPHS) pool_acc[b * REP_STRIDE + t] = 0.f;
        __syncthreads();
        int ebase = b * PAIR_CHUNK;
        int ecount = min(PAIR_CHUNK, N_EDGES - ebase);
        for (int i = t; i < ecount; i += 256)
            atomicAdd(&hcnt[e1[ebase + i] >> BSHIFT], 1);
        __syncthreads();
        for (int i = t; i < NB; i += 256) blockcnt[b * NB + i] = hcnt[i];
    } else if (b < PAIR_BLOCKS + TBL_BLOCKS) {
        // ---- layer-1 table, 4 levels per block (one per wave, shuffle-only) ----
        int l = (b - PAIR_BLOCKS) * 4 + (t >> 6);
        int f = t & 63;
        float r0 = 0.f, r1 = 0.f;
#pragma unroll 8
        for (int k = 0; k < 64; ++k) {
            float w = Ws[k * 64 + f];
            r0 = fmaf(embed[k], w, r0);
            r1 = fmaf(embed[64 + k], w, r1);
        }
        if (l == 0) {  // layer-0 score scalars
            float as = a_srcs[f], ad = a_dsts[f];
            float t0 = r0 * as, t1 = r1 * as, t2 = r0 * ad, t3 = r1 * ad;
#pragma unroll
            for (int off = 32; off >= 1; off >>= 1) {
                t0 += __shfl_xor(t0, off); t1 += __shfl_xor(t1, off);
                t2 += __shfl_xor(t2, off); t3 += __shfl_xor(t3, off);
            }
            if (f == 0) { sparams[0] = t0; sparams[1] = t1; sparams[2] = t2; sparams[3] = t3; }
        }
        if (l == 1) {  // head constant: b2 @ W_out
            float b2 = biases[128 + f];
            float t4 = b2 * W_out[f * 2];
            float t5 = b2 * W_out[f * 2 + 1];
#pragma unroll
            for (int off = 32; off >= 1; off >>= 1) {
                t4 += __shfl_xor(t4, off); t5 += __shfl_xor(t5, off);
            }
            if (f == 0) { sparams[4] = t4; sparams[5] = t5; }
        }
        float c1 = (float)l * (1.f / (NLVL - 1));
        float o = fmaxf(biases[f] + r0 + c1 * (r1 - r0), 0.f);
        const float* W1 = Ws + 4096;
        float h = 0.f;
#pragma unroll 8
        for (int k = 0; k < 64; ++k) h = fmaf(__shfl(o, k), W1[k * 64 + f], h);
        float ss = h * a_srcs[64 + f];
        float sd = h * a_dsts[64 + f];
        float am = fabsf(h);
#pragma unroll
        for (int off = 32; off >= 1; off >>= 1) {
            ss += __shfl_xor(ss, off);
            sd += __shfl_xor(sd, off);
            am = fmaxf(am, __shfl_xor(am, off));
        }
        float iscl = (am > 0.f) ? 127.f / am : 0.f;
        Tq8[l * 64 + f] = (unsigned char)(__float2int_rn(h * iscl) & 255);
        if (f == 0) { Tscl[l] = am * (1.f / 127.f); Ts1s[l] = ss; Ts1d[l] = sd; }
    } else {
        // ---- x bitmask + degree-array zero ----
        int i = (b - PAIR_BLOCKS - TBL_BLOCKS) * 256 + t;
        int lane = t & 63;
        bool bb = (i < N_NODES) && (x[i] != 0);
        unsigned long long m = __ballot(bb);
        int wid = i >> 6;
        if (i < N_NODES + 64) {
            if (lane == 0) xb[wid * 2] = (unsigned)m;
            if (lane == 32) xb[wid * 2 + 1] = (unsigned)(m >> 32);
        }
        if (i < N_NODES) degg[i] = 0;
    }
}

// one wave per bucket: exclusive scan over its chunk counts (in place) + total
__global__ __launch_bounds__(64) void k_scan_bases(int* __restrict__ blockcnt,
                                                   int* __restrict__ btot) {
    int b = blockIdx.x;
    int lane = threadIdx.x;
    int s = 0;
    for (int base = 0; base < PAIR_BLOCKS; base += 64) {
        int c = base + lane;
        int v = (c < PAIR_BLOCKS) ? blockcnt[c * NB + b] : 0;
        int xv = v;
#pragma unroll
        for (int off = 1; off < 64; off <<= 1) {
            int y = __shfl_up(xv, off);
            if (lane >= off) xv += y;
        }
        if (c < PAIR_BLOCKS) blockcnt[c * NB + b] = s + xv - v;
        s += __shfl(xv, 63);
    }
    if (lane == 0) btot[b] = s;
}

// 512 threads: local bucket-base scan + edge scatter; also packed global degree histogram.
__global__ __launch_bounds__(512) void k_pair_scatter(
    const int* __restrict__ e0, const int* __restrict__ e1,
    const unsigned* __restrict__ xb, const int* __restrict__ btot,
    const int* __restrict__ blockcnt, int* __restrict__ degg,
    int* __restrict__ pairs)
{
    __shared__ int tot[512];
    __shared__ int cnt[NB];
    __shared__ int base[NB];
    int t = threadIdx.x, b = blockIdx.x;
    int v = (t < NB) ? btot[t] : 0;
    tot[t] = v;
    __syncthreads();
    for (int off = 1; off < 512; off <<= 1) {
        int u = (t >= off) ? tot[t - off] : 0;
        __syncthreads();
        tot[t] += u;
        __syncthreads();
    }
    if (t < NB) {
        cnt[t] = 0;
        base[t] = (tot[t] - v) + blockcnt[b * NB + t];
    }
    __syncthreads();
    int ebase = b * PAIR_CHUNK;
    int ecount = min(PAIR_CHUNK, N_EDGES - ebase);
    for (int i = t; i < ecount; i += 512) {
        int s = e0[ebase + i];
        int d = e1[ebase + i];
        int xv = (xb[s >> 5] >> (s & 31)) & 1;
        atomicAdd(&degg[d], 1 | (xv << 16));
        int B = d >> BSHIFT;
        int idx = atomicAdd(&cnt[B], 1);
        pairs[base[B] + idx] = (xv << 25) | ((d & 255) << 17) | s;  // x|8b dst|17b src
    }
}

// One block (256 thr) per bucket. Degrees read coalesced from global (precomputed).
// Single pairs pass. Self loop at slot 0. Emits cidx inline.
__global__ __launch_bounds__(256) void k_csr_bucket(
    const int* __restrict__ pairs, const int* __restrict__ btot,
    const int* __restrict__ x, const int* __restrict__ degg,
    const float* __restrict__ sparams,
    int* __restrict__ rowptr, int* __restrict__ col,
    unsigned short* __restrict__ cidx)
{
    __shared__ int excl[256];
    __shared__ int cnt2[256];
    __shared__ int wsum[4];
    __shared__ int p0sh;
    int b = blockIdx.x;
    int t = threadIdx.x;
    int nb = b << BSHIFT;
    int nodes = min(256, N_NODES - nb);

    // p0 = sum of btot[0..b)  (b <= 390; cover with t and t+256)
    int pv = (t < b) ? btot[t] : 0;
    if (t + 256 < b) pv += btot[t + 256];
#pragma unroll
    for (int off = 32; off >= 1; off >>= 1) pv += __shfl_xor(pv, off);
    if ((t & 63) == 0) wsum[t >> 6] = pv;
    __syncthreads();
    if (t == 0) p0sh = wsum[0] + wsum[1] + wsum[2] + wsum[3];

    int xself = (t < nodes) ? (x[nb + t] & 1) : 0;
    int packed = ((t < nodes) ? degg[nb + t] : 0) + ((t < nodes) ? (1 | (xself << 16)) : 0);
    cnt2[t] = 1;  // slot 0 = self loop
    __syncthreads();
    int p0 = p0sh;
    int p1 = p0 + btot[b];

    int val = packed & 0xFFFF;   // degree incl self loop
    int kx = packed >> 16;       // x=1 neighbors incl self
    if (t < nodes) {
        float ss0 = sparams[0], ss1 = sparams[1];
        float sd = xself ? sparams[3] : sparams[2];
        float e0 = ss0 + sd; e0 = (e0 >= 0.f) ? e0 : NEG_SLOPE * e0;
        float e1 = ss1 + sd; e1 = (e1 >= 0.f) ? e1 : NEG_SLOPE * e1;
        float pp0 = __expf(e0), pp1 = __expf(e1);
        float kn = (float)kx, dn = (float)(val - kx);
        float c1 = kn * pp1 / (dn * pp0 + kn * pp1);
        cidx[nb + t] = (unsigned short)__float2int_rn(c1 * (float)(NLVL - 1));
    }

    int xx = val;
#pragma unroll
    for (int off = 1; off < 64; off <<= 1) {
        int y = __shfl_up(xx, off);
        if ((t & 63) >= off) xx += y;
    }
    __syncthreads();
    if ((t & 63) == 63) wsum[t >> 6] = xx;
    __syncthreads();
    if (t == 0) {
        int s = 0;
#pragma unroll
        for (int i = 0; i < 4; ++i) { int v = wsum[i]; wsum[i] = s; s += v; }
    }
    __syncthreads();
    int ex = xx - val + wsum[t >> 6];
    excl[t] = ex;

    int colbase = p0 + nb;  // nb == #self-loops in preceding buckets
    if (t < nodes) {
        rowptr[nb + t] = colbase + ex;
        col[colbase + ex] = nb + t;  // self loop at slot 0
    }
    if (b == NB - 1 && t == 0) rowptr[N_NODES] = ETOT;
    __syncthreads();
    for (int i = p0 + t; i < p1; i += 256) {
        int p = pairs[i];
        int li = (p >> 17) & 255;
        int pos = colbase + excl[li] + atomicAdd(&cnt2[li], 1);
        col[pos] = p & 0x1FFFF;
    }
}

// ---------------- layer-1 agg: 2 nodes per wave, tables via L1 ----------------

__global__ __launch_bounds__(256) void k_agg1(
    const unsigned char* __restrict__ Tq8, const float* __restrict__ Tscl,
    const float* __restrict__ Ts1s, const float* __restrict__ Ts1d,
    const unsigned short* __restrict__ cidx, const int* __restrict__ col,
    const int* __restrict__ rowptr, const float* __restrict__ bias,
    unsigned short* __restrict__ hout)
{
    __shared__ float2 stash[4][64];
    int t = threadIdx.x;
    int wave = t >> 6, lane = t & 63;
    int h = lane >> 5, hl = lane & 31;
    int base = blockIdx.x * 8 + wave * 2;
    if (base >= N_NODES) return;
    const char* hb = (const char*)Tq8;

    int node = base + h;
    bool valid = (node < N_NODES);
    int row = 0, end = 0;
    if (valid) { row = rowptr[node]; end = rowptr[node + 1]; }
    int deg = end - row;
    int degO = __shfl_xor(deg, 32);
    bool fast = (deg <= 32) && (degO <= 32);

    if (fast) {
        int idx = 0;
        float p = 0.f, sc = 0.f;
        if (hl < deg) idx = cidx[col[row + hl]];
        float sdi = Ts1d[__shfl(idx, h * 32)];   // slot 0 = self loop
        if (hl < deg) {
            float ee = Ts1s[idx] + sdi;
            ee = (ee >= 0.f) ? ee : NEG_SLOPE * ee;
            p = __expf(ee);
            sc = Tscl[idx];
        }
        stash[wave][lane] = make_float2(p * sc, __int_as_float(idx * 64));

        int q = hl >> 4;
        int f = hl & 15;
        int f4 = f * 4;
        int sb = h * 32;
        float a0 = 0.f, a1 = 0.f, a2 = 0.f, a3 = 0.f;
        int degr = (deg + 7) & ~7;
        for (int j = q; j < degr; j += 8) {
            float2 e0 = stash[wave][sb + j];
            float2 e1 = stash[wave][sb + j + 2];
            float2 e2 = stash[wave][sb + j + 4];
            float2 e3 = stash[wave][sb + j + 6];
            unsigned v0 = *(const unsigned*)(hb + (__float_as_int(e0.y) + f4));
            unsigned v1 = *(const unsigned*)(hb + (__float_as_int(e1.y) + f4));
            unsigned v2 = *(const unsigned*)(hb + (__float_as_int(e2.y) + f4));
            unsigned v3 = *(const unsigned*)(hb + (__float_as_int(e3.y) + f4));
            a0 = fmaf(e0.x, (float)sb0(v0), a0);
            a1 = fmaf(e0.x, (float)sb1(v0), a1);
            a2 = fmaf(e0.x, (float)sb2(v0), a2);
            a3 = fmaf(e0.x, (float)sb3(v0), a3);
            a0 = fmaf(e1.x, (float)sb0(v1), a0);
            a1 = fmaf(e1.x, (float)sb1(v1), a1);
            a2 = fmaf(e1.x, (float)sb2(v1), a2);
            a3 = fmaf(e1.x, (float)sb3(v1), a3);
            a0 = fmaf(e2.x, (float)sb0(v2), a0);
            a1 = fmaf(e2.x, (float)sb1(v2), a1);
            a2 = fmaf(e2.x, (float)sb2(v2), a2);
            a3 = fmaf(e2.x, (float)sb3(v2), a3);
            a0 = fmaf(e3.x, (float)sb0(v3), a0);
            a1 = fmaf(e3.x, (float)sb1(v3), a1);
            a2 = fmaf(e3.x, (float)sb2(v3), a2);
            a3 = fmaf(e3.x, (float)sb3(v3), a3);
        }
        float denom = p;
#pragma unroll
        for (int off = 16; off >= 1; off >>= 1) denom += __shfl_xor(denom, off);
        float inv = 1.f / denom;
        a0 += __shfl_xor(a0, 16);
        a1 += __shfl_xor(a1, 16);
        a2 += __shfl_xor(a2, 16);
        a3 += __shfl_xor(a3, 16);
        if (hl < 16 && valid) {
            float4 bb = *(const float4*)&bias[4 * f];
            ushort4 pk;
            pk.x = f2bf(fmaxf(fmaf(a0, inv, bb.x), 0.f));
            pk.y = f2bf(fmaxf(fmaf(a1, inv, bb.y), 0.f));
            pk.z = f2bf(fmaxf(fmaf(a2, inv, bb.z), 0.f));
            pk.w = f2bf(fmaxf(fmaf(a3, inv, bb.w), 0.f));
            *(ushort4*)&hout[node * 64 + 4 * f] = pk;
        }
    } else {
        // rare: per-pair generic full-wave path
        for (int s = 0; s < 2; ++s) {
            int nd = base + s;
            if (nd >= N_NODES) continue;
            int r = rowptr[nd], e = rowptr[nd + 1];
            float sdi = Ts1d[cidx[nd]];
            float m = -FLT_MAX;
            for (int j = r + lane; j < e; j += 64) {
                float ee = Ts1s[cidx[col[j]]] + sdi;
                ee = (ee >= 0.f) ? ee : NEG_SLOPE * ee;
                m = fmaxf(m, ee);
            }
#pragma unroll
            for (int off = 32; off >= 1; off >>= 1) m = fmaxf(m, __shfl_xor(m, off));
            float denom = 0.f;
            for (int j = r + lane; j < e; j += 64) {
                float ee = Ts1s[cidx[col[j]]] + sdi;
                ee = (ee >= 0.f) ? ee : NEG_SLOPE * ee;
                denom += __expf(ee - m);
            }
#pragma unroll
            for (int off = 32; off >= 1; off >>= 1) denom += __shfl_xor(denom, off);
            float inv = 1.f / denom;
            float acc = 0.f;
            for (int j = r; j < e; ++j) {
                int idxj = cidx[col[j]];
                float ee = Ts1s[idxj] + sdi;
                ee = (ee >= 0.f) ? ee : NEG_SLOPE * ee;
                float w = __expf(ee - m) * inv * Tscl[idxj];
                int bq = (int)(signed char)Tq8[idxj * 64 + lane];
                acc = fmaf(w, (float)bq, acc);
            }
            hout[nd * 64 + lane] = f2bf(fmaxf(acc + bias[lane], 0.f));
        }
    }
}

// ---------------- layer-2 GEMM: scores + z = h2 @ W_out (8 B per node) ----------------

__global__ __launch_bounds__(256) void k_gemm2(
    const unsigned* __restrict__ h32, const float* __restrict__ W,
    const float* __restrict__ a_s, const float* __restrict__ a_d,
    const float* __restrict__ W_out,
    float2* __restrict__ z2, float* __restrict__ s_src, float* __restrict__ s_dst)
{
    __shared__ float Wl[64 * 64];
    __shared__ float hT[64 * 68];  // [k][r], pitch 68
    int t = threadIdx.x;
    int r0 = blockIdx.x * 64;

    for (int i = t; i < 4096; i += 256) Wl[i] = W[i];
    for (int i = t; i < 2048; i += 256) {
        int r = i >> 5, m = i & 31;
        int row = r0 + r;
        unsigned u = (row < N_NODES) ? h32[row * 32 + m] : 0u;
        hT[(2 * m) * 68 + r]     = blo(u);
        hT[(2 * m + 1) * 68 + r] = bhi(u);
    }
    __syncthreads();

    int tcol = t & 15;
    int trow = t >> 4;
    float acc[4][4];
#pragma unroll
    for (int i = 0; i < 4; ++i)
#pragma unroll
        for (int j = 0; j < 4; ++j) acc[i][j] = 0.f;

    for (int k = 0; k < 64; ++k) {
        float4 va = *(const float4*)&hT[k * 68 + trow * 4];
        float4 vb = *(const float4*)&Wl[k * 64 + tcol * 4];
        float a[4] = {va.x, va.y, va.z, va.w};
        float bb[4] = {vb.x, vb.y, vb.z, vb.w};
#pragma unroll
        for (int i = 0; i < 4; ++i)
#pragma unroll
            for (int j = 0; j < 4; ++j) acc[i][j] = fmaf(a[i], bb[j], acc[i][j]);
    }

    float4 as4 = *(const float4*)&a_s[tcol * 4];
    float4 ad4 = *(const float4*)&a_d[tcol * 4];
    float asr[4] = {as4.x, as4.y, as4.z, as4.w};
    float adr[4] = {ad4.x, ad4.y, ad4.z, ad4.w};
    float4 wa = *(const float4*)&W_out[8 * tcol];
    float4 wb = *(const float4*)&W_out[8 * tcol + 4];

#pragma unroll
    for (int i = 0; i < 4; ++i) {
        int row = r0 + trow * 4 + i;
        float ps = 0.f, pd = 0.f;
#pragma unroll
        for (int j = 0; j < 4; ++j) {
            ps = fmaf(acc[i][j], asr[j], ps);
            pd = fmaf(acc[i][j], adr[j], pd);
        }
        float z0 = acc[i][0] * wa.x + acc[i][1] * wa.z + acc[i][2] * wb.x + acc[i][3] * wb.z;
        float z1 = acc[i][0] * wa.y + acc[i][1] * wa.w + acc[i][2] * wb.y + acc[i][3] * wb.w;
#pragma unroll
        for (int off = 8; off >= 1; off >>= 1) {
            ps += __shfl_xor(ps, off);
            pd += __shfl_xor(pd, off);
            z0 += __shfl_xor(z0, off);
            z1 += __shfl_xor(z1, off);
        }
        if (row < N_NODES && tcol == 0) {
            s_src[row] = ps; s_dst[row] = pd;
            z2[row] = make_float2(z0, z1);
        }
    }
}

// ---------------- last-layer agg + pool: 2 nodes/wave x 4 pairs, register g-accumulation ----------------

__global__ __launch_bounds__(256) void k_pool2(
    const float2* __restrict__ z2, const int* __restrict__ col,
    const int* __restrict__ rowptr, const float* __restrict__ s_src_in,
    const float* __restrict__ s_dst_in, const int* __restrict__ batch,
    float* __restrict__ pool_acc)
{
    int t = threadIdx.x;
    int wave = t >> 6, lane = t & 63;
    int h = lane >> 5, hl = lane & 31;
    int base0 = blockIdx.x * 32 + wave * 8;
    if (base0 >= N_NODES) return;
    float* rep = pool_acc + ((blockIdx.x * 4 + wave) & (NREP - 1)) * REP_STRIDE;

    int gcur = -1;
    float acc0 = 0.f, acc1 = 0.f;

#pragma unroll
    for (int i = 0; i < 4; ++i) {
        int node = base0 + 2 * i + h;
        bool valid = (node < N_NODES);
        int row = 0, end = 0;
        if (valid) { row = rowptr[node]; end = rowptr[node + 1]; }
        int deg = end - row;
        int degO = __shfl_xor(deg, 32);
        bool fast = (deg <= 32) && (degO <= 32);
        float r0 = 0.f, r1 = 0.f;

        if (fast) {
            float sdi = valid ? s_dst_in[node] : 0.f;
            float p = 0.f;
            float2 zv = make_float2(0.f, 0.f);
            if (hl < deg) {
                int c = col[row + hl];
                float ee = s_src_in[c] + sdi;
                ee = (ee >= 0.f) ? ee : NEG_SLOPE * ee;
                p = __expf(ee);
                zv = z2[c];
            }
            float n0 = p * zv.x, n1 = p * zv.y, dn = p;
#pragma unroll
            for (int off = 16; off >= 1; off >>= 1) {
                n0 += __shfl_xor(n0, off);
                n1 += __shfl_xor(n1, off);
                dn += __shfl_xor(dn, off);
            }
            float inv = 1.f / dn;
            r0 = n0 * inv; r1 = n1 * inv;
        } else {
            float rr0[2], rr1[2];
#pragma unroll
            for (int s = 0; s < 2; ++s) {
                rr0[s] = rr1[s] = 0.f;
                int nd = base0 + 2 * i + s;
                if (nd >= N_NODES) continue;
                int r = rowptr[nd], e = rowptr[nd + 1];
                float sdi = s_dst_in[nd];
                float n0 = 0.f, n1 = 0.f, dn = 0.f;
                for (int j = r + lane; j < e; j += 64) {
                    int c = col[j];
                    float ee = s_src_in[c] + sdi;
                    ee = (ee >= 0.f) ? ee : NEG_SLOPE * ee;
                    float p = __expf(ee);
                    float2 zv = z2[c];
                    n0 = fmaf(p, zv.x, n0);
                    n1 = fmaf(p, zv.y, n1);
                    dn += p;
                }
#pragma unroll
                for (int off = 32; off >= 1; off >>= 1) {
                    n0 += __shfl_xor(n0, off);
                    n1 += __shfl_xor(n1, off);
                    dn += __shfl_xor(dn, off);
                }
                float inv = 1.f / dn;
                rr0[s] = n0 * inv; rr1[s] = n1 * inv;
            }
            r0 = rr0[h]; r1 = rr1[h];
        }

        if (hl == 0 && valid) {
            int g = batch[node];
            if (g != gcur) {
                if (gcur >= 0) {
                    atomicAdd(&rep[gcur * 2], acc0);
                    atomicAdd(&rep[gcur * 2 + 1], acc1);
                }
                gcur = g; acc0 = r0; acc1 = r1;
            } else {
                acc0 += r0; acc1 += r1;
            }
        }
    }
    if (hl == 0 && gcur >= 0) {
        atomicAdd(&rep[gcur * 2], acc0);
        atomicAdd(&rep[gcur * 2 + 1], acc1);
    }
}

// ---------------- head: reduce replicas, divide by count, add consts ----------------

__device__ __forceinline__ int lower_bound_dev(const int* __restrict__ a, int n, int v) {
    int lo = 0, hi = n;
    while (lo < hi) {
        int mid = (lo + hi) >> 1;
        if (a[mid] < v) lo = mid + 1; else hi = mid;
    }
    return lo;
}

__global__ void k_head(const float* __restrict__ pool_acc,
                       const int* __restrict__ batch,
                       const float* __restrict__ b_out,
                       const float* __restrict__ sparams,
                       float* __restrict__ out)
{
    int t = threadIdx.x;
    if (t < 2 * N_GRAPHS) {
        float s = 0.f;
#pragma unroll 8
        for (int r = 0; r < NREP; ++r) s += pool_acc[r * REP_STRIDE + t];
        int g = t >> 1, c = t & 1;
        int start = lower_bound_dev(batch, N_NODES, g);
        int end = lower_bound_dev(batch, N_NODES, g + 1);
        float cnt = fmaxf((float)(end - start), 1.f);
        out[t] = s / cnt + sparams[4 + c] + b_out[c];
    }
}

// ---------------- launch ----------------

extern "C" void kernel_launch(void* const* d_in, const int* in_sizes, int n_in,
                              void* d_out, int out_size, void* d_ws, size_t ws_size,
                              hipStream_t stream) {
    const int*   x       = (const int*)d_in[0];
    const int*   edge    = (const int*)d_in[1];   // [2][E]
    const int*   batch   = (const int*)d_in[2];
    const float* embed   = (const float*)d_in[3];
    const float* Ws      = (const float*)d_in[4];
    const float* a_srcs  = (const float*)d_in[5];
    const float* a_dsts  = (const float*)d_in[6];
    const float* biases  = (const float*)d_in[7];
    const float* W_out   = (const float*)d_in[8];
    const float* b_out   = (const float*)d_in[9];
    float* out = (float*)d_out;

    char* ws = (char*)d_ws;
    size_t off = 0;
    auto alloc = [&](size_t bytes) -> void* {
        void* p = ws + off;
        off += (bytes + 255) & ~(size_t)255;
        return p;
    };
    unsigned short* hout  = (unsigned short*)alloc((size_t)N_NODES * 64 * sizeof(unsigned short));
    float2* z2      = (float2*)alloc((size_t)N_NODES * sizeof(float2));
    float* s_src0   = (float*)alloc((size_t)N_NODES * sizeof(float));
    float* s_dst0   = (float*)alloc((size_t)N_NODES * sizeof(float));
    unsigned short* cidx = (unsigned short*)alloc((size_t)N_NODES * sizeof(unsigned short));
    int*   degg     = (int*)alloc((size_t)N_NODES * sizeof(int));
    int*   rowptr   = (int*)alloc((size_t)(N_NODES + 1) * sizeof(int));
    int*   colA     = (int*)alloc((size_t)ETOT * sizeof(int));
    int*   blockcnt = (int*)alloc((size_t)PAIR_BLOCKS * NB * sizeof(int));
    int*   btot     = (int*)alloc((size_t)NB * sizeof(int));
    float* pool_acc = (float*)alloc((size_t)(NREP * REP_STRIDE) * sizeof(float));
    unsigned* xb    = (unsigned*)alloc((size_t)3232 * sizeof(unsigned));
    unsigned char* Tq8 = (unsigned char*)alloc((size_t)NLVL * 64);
    float* Tscl     = (float*)alloc((size_t)NLVL * sizeof(float));
    float* Ts1s     = (float*)alloc((size_t)NLVL * sizeof(float));
    float* Ts1d     = (float*)alloc((size_t)NLVL * sizeof(float));
    float* sparams  = (float*)alloc((size_t)8 * sizeof(float));
    int*   pairs    = (int*)alloc((size_t)N_EDGES * sizeof(int));  // dead after CSR build

    const int* e0 = edge;
    const int* e1 = edge + N_EDGES;

    // fused prep: bucket counts | layer-1 table | x bitmask + deg zero
    k_prep<<<PAIR_BLOCKS + TBL_BLOCKS + XBIT_BLOCKS, 256, 0, stream>>>(
        e1, x, embed, Ws, biases, a_srcs, a_dsts, W_out,
        blockcnt, pool_acc, xb, degg, Tq8, Tscl, Ts1s, Ts1d, sparams);
    k_scan_bases<<<NB, 64, 0, stream>>>(blockcnt, btot);
    k_pair_scatter<<<PAIR_BLOCKS, 512, 0, stream>>>(e0, e1, xb, btot, blockcnt, degg, pairs);
    k_csr_bucket<<<NB, 256, 0, stream>>>(pairs, btot, x, degg, sparams, rowptr, colA, cidx);

    // layer 1: table-based aggregation (2 nodes/wave) -> bf16 hout
    k_agg1<<<(N_NODES + 7) / 8, 256, 0, stream>>>(
        Tq8, Tscl, Ts1s, Ts1d, cidx, colA, rowptr, biases + 64, hout);
    // layer 2: GEMM -> scores + z, then 8-B-gather pool
    k_gemm2<<<(N_NODES + 63) / 64, 256, 0, stream>>>(
        (const unsigned*)hout, Ws + 8192, a_srcs + 128, a_dsts + 128, W_out,
        z2, s_src0, s_dst0);
    k_pool2<<<(N_NODES + 31) / 32, 256, 0, stream>>>(
        z2, colA, rowptr, s_src0, s_dst0, batch, pool_acc);
    k_head<<<1, 256, 0, stream>>>(pool_acc, batch, b_out, sparams, out);
}

// Round 18
// 212.681 us; speedup vs baseline: 1.2533x; 1.2533x over previous
//
#include <hip/hip_runtime.h>
#include <hip/hip_bf16.h>
#include <float.h>

#define N_NODES 100000
#define N_EDGES 1600000
#define HIDDEN 64
#define N_GRAPHS 128
#define NEG_SLOPE 0.2f
#define ETOT (N_EDGES + N_NODES)

#define BSHIFT 9
#define NB ((N_NODES + 511) >> BSHIFT)    // 196 buckets of 512 nodes
#define PAIR_CHUNK 4096
#define PAIR_BLOCKS ((N_EDGES + PAIR_CHUNK - 1) / PAIR_CHUNK)  // 391
#define XBIT_BLOCKS ((N_NODES + 255) / 256)                     // 391
#define TBL_BLOCKS (NLVL / 4)                                   // 128

#define NREP 64           // pool accumulator replicas
#define REP_STRIDE 272
#define NLVL 512          // c1 quantization levels (layer-1 table)

__device__ __forceinline__ unsigned short f2bf(float f) {
    unsigned u = __float_as_uint(f);
    unsigned r = (u + 0x7FFFu + ((u >> 16) & 1u)) >> 16;  // RNE
    return (unsigned short)r;
}
__device__ __forceinline__ float blo(unsigned u) { return __uint_as_float(u << 16); }
__device__ __forceinline__ float bhi(unsigned u) { return __uint_as_float(u & 0xFFFF0000u); }
__device__ __forceinline__ int sb0(unsigned u) { return (int)((unsigned)(u << 24)) >> 24; }
__device__ __forceinline__ int sb1(unsigned u) { return (int)((unsigned)(u << 16)) >> 24; }
__device__ __forceinline__ int sb2(unsigned u) { return (int)((unsigned)(u << 8)) >> 24; }
__device__ __forceinline__ int sb3(unsigned u) { return (int)u >> 24; }

// ---------------- fused prep: edge bucket counts | layer-1 table | x bitmask ----------------

__global__ __launch_bounds__(256) void k_prep(
    const int* __restrict__ e1, const int* __restrict__ x,
    const float* __restrict__ embed, const float* __restrict__ Ws,
    const float* __restrict__ biases, const float* __restrict__ a_srcs,
    const float* __restrict__ a_dsts, const float* __restrict__ W_out,
    int* __restrict__ blockcnt, float* __restrict__ pool_acc,
    unsigned* __restrict__ xb,
    unsigned char* __restrict__ Tq8, float* __restrict__ Tscl,
    float* __restrict__ Ts1s, float* __restrict__ Ts1d,
    float* __restrict__ sparams)
{
    __shared__ int hcnt[NB];
    int t = threadIdx.x, b = blockIdx.x;

    if (b < PAIR_BLOCKS) {
        // ---- bucket counts for chunk b (+ zero pool_acc replicas) ----
        if (t < NB) hcnt[t] = 0;
        if (b < NREP && t < 2 * N_GRAPHS) pool_acc[b * REP_STRIDE + t] = 0.f;
        __syncthreads();
        int ebase = b * PAIR_CHUNK;
        int ecount = min(PAIR_CHUNK, N_EDGES - ebase);
        for (int i = t; i < ecount; i += 256)
            atomicAdd(&hcnt[e1[ebase + i] >> BSHIFT], 1);
        __syncthreads();
        if (t < NB) blockcnt[b * NB + t] = hcnt[t];
    } else if (b < PAIR_BLOCKS + TBL_BLOCKS) {
        // ---- layer-1 table, 4 levels per block (one per wave, shuffle-only) ----
        int l = (b - PAIR_BLOCKS) * 4 + (t >> 6);
        int f = t & 63;
        float r0 = 0.f, r1 = 0.f;
#pragma unroll 8
        for (int k = 0; k < 64; ++k) {
            float w = Ws[k * 64 + f];
            r0 = fmaf(embed[k], w, r0);
            r1 = fmaf(embed[64 + k], w, r1);
        }
        if (l == 0) {  // layer-0 score scalars
            float as = a_srcs[f], ad = a_dsts[f];
            float t0 = r0 * as, t1 = r1 * as, t2 = r0 * ad, t3 = r1 * ad;
#pragma unroll
            for (int off = 32; off >= 1; off >>= 1) {
                t0 += __shfl_xor(t0, off); t1 += __shfl_xor(t1, off);
                t2 += __shfl_xor(t2, off); t3 += __shfl_xor(t3, off);
            }
            if (f == 0) { sparams[0] = t0; sparams[1] = t1; sparams[2] = t2; sparams[3] = t3; }
        }
        if (l == 1) {  // head constant: b2 @ W_out
            float b2 = biases[128 + f];
            float t4 = b2 * W_out[f * 2];
            float t5 = b2 * W_out[f * 2 + 1];
#pragma unroll
            for (int off = 32; off >= 1; off >>= 1) {
                t4 += __shfl_xor(t4, off); t5 += __shfl_xor(t5, off);
            }
            if (f == 0) { sparams[4] = t4; sparams[5] = t5; }
        }
        float c1 = (float)l * (1.f / (NLVL - 1));
        float o = fmaxf(biases[f] + r0 + c1 * (r1 - r0), 0.f);
        const float* W1 = Ws + 4096;
        float h = 0.f;
#pragma unroll 8
        for (int k = 0; k < 64; ++k) h = fmaf(__shfl(o, k), W1[k * 64 + f], h);
        float ss = h * a_srcs[64 + f];
        float sd = h * a_dsts[64 + f];
        float am = fabsf(h);
#pragma unroll
        for (int off = 32; off >= 1; off >>= 1) {
            ss += __shfl_xor(ss, off);
            sd += __shfl_xor(sd, off);
            am = fmaxf(am, __shfl_xor(am, off));
        }
        float iscl = (am > 0.f) ? 127.f / am : 0.f;
        Tq8[l * 64 + f] = (unsigned char)(__float2int_rn(h * iscl) & 255);
        if (f == 0) { Tscl[l] = am * (1.f / 127.f); Ts1s[l] = ss; Ts1d[l] = sd; }
    } else {
        // ---- x bitmask ----
        int i = (b - PAIR_BLOCKS - TBL_BLOCKS) * 256 + t;
        int lane = t & 63;
        bool bb = (i < N_NODES) && (x[i] != 0);
        unsigned long long m = __ballot(bb);
        int wid = i >> 6;
        if (i < N_NODES + 64) {
            if (lane == 0) xb[wid * 2] = (unsigned)m;
            if (lane == 32) xb[wid * 2 + 1] = (unsigned)(m >> 32);
        }
    }
}

// one wave per bucket: exclusive scan over its chunk counts (in place) + total
__global__ __launch_bounds__(64) void k_scan_bases(int* __restrict__ blockcnt,
                                                   int* __restrict__ btot) {
    int b = blockIdx.x;
    int lane = threadIdx.x;
    int s = 0;
    for (int base = 0; base < PAIR_BLOCKS; base += 64) {
        int c = base + lane;
        int v = (c < PAIR_BLOCKS) ? blockcnt[c * NB + b] : 0;
        int xv = v;
#pragma unroll
        for (int off = 1; off < 64; off <<= 1) {
            int y = __shfl_up(xv, off);
            if (lane >= off) xv += y;
        }
        if (c < PAIR_BLOCKS) blockcnt[c * NB + b] = s + xv - v;
        s += __shfl(xv, 63);
    }
    if (lane == 0) btot[b] = s;
}

__global__ __launch_bounds__(256) void k_pair_scatter(
    const int* __restrict__ e0, const int* __restrict__ e1,
    const unsigned* __restrict__ xb, const int* __restrict__ btot,
    const int* __restrict__ blockcnt, int* __restrict__ pairs)
{
    __shared__ int tot[256];
    __shared__ int cnt[NB];
    __shared__ int base[NB];
    int t = threadIdx.x, b = blockIdx.x;
    // local exclusive scan of bucket totals -> pair_start
    int v = (t < NB) ? btot[t] : 0;
    tot[t] = v;
    __syncthreads();
    for (int off = 1; off < 256; off <<= 1) {
        int u = (t >= off) ? tot[t - off] : 0;
        __syncthreads();
        tot[t] += u;
        __syncthreads();
    }
    if (t < NB) {
        cnt[t] = 0;
        base[t] = (tot[t] - v) + blockcnt[b * NB + t];
    }
    __syncthreads();
    int ebase = b * PAIR_CHUNK;
    int ecount = min(PAIR_CHUNK, N_EDGES - ebase);
    for (int i = t; i < ecount; i += 256) {
        int s = e0[ebase + i];
        int d = e1[ebase + i];
        int xv = (xb[s >> 5] >> (s & 31)) & 1;
        int B = d >> BSHIFT;
        int idx = atomicAdd(&cnt[B], 1);
        pairs[base[B] + idx] = (xv << 26) | ((d & 511) << 17) | s;  // x|9b dst|17b src
    }
}

// One block (512 thr) per bucket. Self loop at slot 0. Emits cidx inline.
__global__ __launch_bounds__(512) void k_csr_bucket(
    const int* __restrict__ pairs, const int* __restrict__ btot,
    const int* __restrict__ x, const float* __restrict__ sparams,
    int* __restrict__ rowptr, int* __restrict__ col,
    unsigned short* __restrict__ cidx)
{
    __shared__ int deg[512];
    __shared__ int excl[512];
    __shared__ int cnt2[512];
    __shared__ int wsum[8];
    __shared__ int p0sh;
    int b = blockIdx.x;
    int t = threadIdx.x;
    int nb = b << BSHIFT;
    int nodes = min(512, N_NODES - nb);

    // local reduce: p0 = sum of btot[0..b)
    int pv = (t < b) ? btot[t] : 0;   // b < NB <= 196 < 512
#pragma unroll
    for (int off = 32; off >= 1; off >>= 1) pv += __shfl_xor(pv, off);
    if ((t & 63) == 0) wsum[t >> 6] = pv;
    __syncthreads();
    if (t == 0) {
        int s = 0;
#pragma unroll
        for (int i = 0; i < 8; ++i) s += wsum[i];
        p0sh = s;
    }

    int xself = (t < nodes) ? (x[nb + t] & 1) : 0;
    deg[t] = (t < nodes) ? (1 | (xself << 16)) : 0;   // self loop contributes
    cnt2[t] = 1;
    __syncthreads();
    int p0 = p0sh;
    int p1 = p0 + btot[b];
    for (int i = p0 + t; i < p1; i += 512) {
        int p = pairs[i];
        atomicAdd(&deg[(p >> 17) & 511], 1 | (((p >> 26) & 1) << 16));
    }
    __syncthreads();

    int packed = deg[t];
    int val = packed & 0xFFFF;
    int kx = packed >> 16;
    if (t < nodes) {
        float ss0 = sparams[0], ss1 = sparams[1];
        float sd = xself ? sparams[3] : sparams[2];
        float e0 = ss0 + sd; e0 = (e0 >= 0.f) ? e0 : NEG_SLOPE * e0;
        float e1 = ss1 + sd; e1 = (e1 >= 0.f) ? e1 : NEG_SLOPE * e1;
        float pp0 = __expf(e0), pp1 = __expf(e1);
        float kn = (float)kx, dn = (float)(val - kx);
        float c1 = kn * pp1 / (dn * pp0 + kn * pp1);
        cidx[nb + t] = (unsigned short)__float2int_rn(c1 * (float)(NLVL - 1));
    }

    int xx = val;
#pragma unroll
    for (int off = 1; off < 64; off <<= 1) {
        int y = __shfl_up(xx, off);
        if ((t & 63) >= off) xx += y;
    }
    __syncthreads();
    if ((t & 63) == 63) wsum[t >> 6] = xx;
    __syncthreads();
    if (t == 0) {
        int s = 0;
#pragma unroll
        for (int i = 0; i < 8; ++i) { int v = wsum[i]; wsum[i] = s; s += v; }
    }
    __syncthreads();
    int ex = xx - val + wsum[t >> 6];
    excl[t] = ex;

    int colbase = p0 + nb;
    if (t < nodes) {
        rowptr[nb + t] = colbase + ex;
        col[colbase + ex] = nb + t;  // self loop at slot 0
    }
    if (b == NB - 1 && t == 0) rowptr[N_NODES] = ETOT;
    __syncthreads();
    for (int i = p0 + t; i < p1; i += 512) {
        int p = pairs[i];
        int li = (p >> 17) & 511;
        int pos = colbase + excl[li] + atomicAdd(&cnt2[li], 1);
        col[pos] = p & 0x1FFFF;
    }
}

// ---------------- layer-1 agg: 2 nodes per wave, tables via L1 ----------------

__global__ __launch_bounds__(256) void k_agg1(
    const unsigned char* __restrict__ Tq8, const float* __restrict__ Tscl,
    const float* __restrict__ Ts1s, const float* __restrict__ Ts1d,
    const unsigned short* __restrict__ cidx, const int* __restrict__ col,
    const int* __restrict__ rowptr, const float* __restrict__ bias,
    unsigned short* __restrict__ hout)
{
    __shared__ float2 stash[4][64];
    int t = threadIdx.x;
    int wave = t >> 6, lane = t & 63;
    int h = lane >> 5, hl = lane & 31;
    int base = blockIdx.x * 8 + wave * 2;
    if (base >= N_NODES) return;
    const char* hb = (const char*)Tq8;

    int node = base + h;
    bool valid = (node < N_NODES);
    int row = 0, end = 0;
    if (valid) { row = rowptr[node]; end = rowptr[node + 1]; }
    int deg = end - row;
    int degO = __shfl_xor(deg, 32);
    bool fast = (deg <= 32) && (degO <= 32);

    if (fast) {
        int idx = 0;
        float p = 0.f, sc = 0.f;
        if (hl < deg) idx = cidx[col[row + hl]];
        float sdi = Ts1d[__shfl(idx, h * 32)];   // slot 0 = self loop
        if (hl < deg) {
            float ee = Ts1s[idx] + sdi;
            ee = (ee >= 0.f) ? ee : NEG_SLOPE * ee;
            p = __expf(ee);
            sc = Tscl[idx];
        }
        stash[wave][lane] = make_float2(p * sc, __int_as_float(idx * 64));

        int q = hl >> 4;
        int f = hl & 15;
        int f4 = f * 4;
        int sb = h * 32;
        float a0 = 0.f, a1 = 0.f, a2 = 0.f, a3 = 0.f;
        int degr = (deg + 7) & ~7;
        for (int j = q; j < degr; j += 8) {
            float2 e0 = stash[wave][sb + j];
            float2 e1 = stash[wave][sb + j + 2];
            float2 e2 = stash[wave][sb + j + 4];
            float2 e3 = stash[wave][sb + j + 6];
            unsigned v0 = *(const unsigned*)(hb + (__float_as_int(e0.y) + f4));
            unsigned v1 = *(const unsigned*)(hb + (__float_as_int(e1.y) + f4));
            unsigned v2 = *(const unsigned*)(hb + (__float_as_int(e2.y) + f4));
            unsigned v3 = *(const unsigned*)(hb + (__float_as_int(e3.y) + f4));
            a0 = fmaf(e0.x, (float)sb0(v0), a0);
            a1 = fmaf(e0.x, (float)sb1(v0), a1);
            a2 = fmaf(e0.x, (float)sb2(v0), a2);
            a3 = fmaf(e0.x, (float)sb3(v0), a3);
            a0 = fmaf(e1.x, (float)sb0(v1), a0);
            a1 = fmaf(e1.x, (float)sb1(v1), a1);
            a2 = fmaf(e1.x, (float)sb2(v1), a2);
            a3 = fmaf(e1.x, (float)sb3(v1), a3);
            a0 = fmaf(e2.x, (float)sb0(v2), a0);
            a1 = fmaf(e2.x, (float)sb1(v2), a1);
            a2 = fmaf(e2.x, (float)sb2(v2), a2);
            a3 = fmaf(e2.x, (float)sb3(v2), a3);
            a0 = fmaf(e3.x, (float)sb0(v3), a0);
            a1 = fmaf(e3.x, (float)sb1(v3), a1);
            a2 = fmaf(e3.x, (float)sb2(v3), a2);
            a3 = fmaf(e3.x, (float)sb3(v3), a3);
        }
        float denom = p;
#pragma unroll
        for (int off = 16; off >= 1; off >>= 1) denom += __shfl_xor(denom, off);
        float inv = 1.f / denom;
        a0 += __shfl_xor(a0, 16);
        a1 += __shfl_xor(a1, 16);
        a2 += __shfl_xor(a2, 16);
        a3 += __shfl_xor(a3, 16);
        if (hl < 16 && valid) {
            float4 bb = *(const float4*)&bias[4 * f];
            ushort4 pk;
            pk.x = f2bf(fmaxf(fmaf(a0, inv, bb.x), 0.f));
            pk.y = f2bf(fmaxf(fmaf(a1, inv, bb.y), 0.f));
            pk.z = f2bf(fmaxf(fmaf(a2, inv, bb.z), 0.f));
            pk.w = f2bf(fmaxf(fmaf(a3, inv, bb.w), 0.f));
            *(ushort4*)&hout[node * 64 + 4 * f] = pk;
        }
    } else {
        // rare: per-pair generic full-wave path
        for (int s = 0; s < 2; ++s) {
            int nd = base + s;
            if (nd >= N_NODES) continue;
            int r = rowptr[nd], e = rowptr[nd + 1];
            float sdi = Ts1d[cidx[nd]];
            float m = -FLT_MAX;
            for (int j = r + lane; j < e; j += 64) {
                float ee = Ts1s[cidx[col[j]]] + sdi;
                ee = (ee >= 0.f) ? ee : NEG_SLOPE * ee;
                m = fmaxf(m, ee);
            }
#pragma unroll
            for (int off = 32; off >= 1; off >>= 1) m = fmaxf(m, __shfl_xor(m, off));
            float denom = 0.f;
            for (int j = r + lane; j < e; j += 64) {
                float ee = Ts1s[cidx[col[j]]] + sdi;
                ee = (ee >= 0.f) ? ee : NEG_SLOPE * ee;
                denom += __expf(ee - m);
            }
#pragma unroll
            for (int off = 32; off >= 1; off >>= 1) denom += __shfl_xor(denom, off);
            float inv = 1.f / denom;
            float acc = 0.f;
            for (int j = r; j < e; ++j) {
                int idxj = cidx[col[j]];
                float ee = Ts1s[idxj] + sdi;
                ee = (ee >= 0.f) ? ee : NEG_SLOPE * ee;
                float w = __expf(ee - m) * inv * Tscl[idxj];
                int bq = (int)(signed char)Tq8[idxj * 64 + lane];
                acc = fmaf(w, (float)bq, acc);
            }
            hout[nd * 64 + lane] = f2bf(fmaxf(acc + bias[lane], 0.f));
        }
    }
}

// ---------------- layer-2 GEMM: scores + z = h2 @ W_out (8 B per node) ----------------

__global__ __launch_bounds__(256) void k_gemm2(
    const unsigned* __restrict__ h32, const float* __restrict__ W,
    const float* __restrict__ a_s, const float* __restrict__ a_d,
    const float* __restrict__ W_out,
    float2* __restrict__ z2, float* __restrict__ s_src, float* __restrict__ s_dst)
{
    __shared__ float Wl[64 * 64];
    __shared__ float hT[64 * 68];  // [k][r], pitch 68
    int t = threadIdx.x;
    int r0 = blockIdx.x * 64;

    for (int i = t; i < 4096; i += 256) Wl[i] = W[i];
    for (int i = t; i < 2048; i += 256) {
        int r = i >> 5, m = i & 31;
        int row = r0 + r;
        unsigned u = (row < N_NODES) ? h32[row * 32 + m] : 0u;
        hT[(2 * m) * 68 + r]     = blo(u);
        hT[(2 * m + 1) * 68 + r] = bhi(u);
    }
    __syncthreads();

    int tcol = t & 15;
    int trow = t >> 4;
    float acc[4][4];
#pragma unroll
    for (int i = 0; i < 4; ++i)
#pragma unroll
        for (int j = 0; j < 4; ++j) acc[i][j] = 0.f;

    for (int k = 0; k < 64; ++k) {
        float4 va = *(const float4*)&hT[k * 68 + trow * 4];
        float4 vb = *(const float4*)&Wl[k * 64 + tcol * 4];
        float a[4] = {va.x, va.y, va.z, va.w};
        float bb[4] = {vb.x, vb.y, vb.z, vb.w};
#pragma unroll
        for (int i = 0; i < 4; ++i)
#pragma unroll
            for (int j = 0; j < 4; ++j) acc[i][j] = fmaf(a[i], bb[j], acc[i][j]);
    }

    float4 as4 = *(const float4*)&a_s[tcol * 4];
    float4 ad4 = *(const float4*)&a_d[tcol * 4];
    float asr[4] = {as4.x, as4.y, as4.z, as4.w};
    float adr[4] = {ad4.x, ad4.y, ad4.z, ad4.w};
    float4 wa = *(const float4*)&W_out[8 * tcol];
    float4 wb = *(const float4*)&W_out[8 * tcol + 4];

#pragma unroll
    for (int i = 0; i < 4; ++i) {
        int row = r0 + trow * 4 + i;
        float ps = 0.f, pd = 0.f;
#pragma unroll
        for (int j = 0; j < 4; ++j) {
            ps = fmaf(acc[i][j], asr[j], ps);
            pd = fmaf(acc[i][j], adr[j], pd);
        }
        float z0 = acc[i][0] * wa.x + acc[i][1] * wa.z + acc[i][2] * wb.x + acc[i][3] * wb.z;
        float z1 = acc[i][0] * wa.y + acc[i][1] * wa.w + acc[i][2] * wb.y + acc[i][3] * wb.w;
#pragma unroll
        for (int off = 8; off >= 1; off >>= 1) {
            ps += __shfl_xor(ps, off);
            pd += __shfl_xor(pd, off);
            z0 += __shfl_xor(z0, off);
            z1 += __shfl_xor(z1, off);
        }
        if (row < N_NODES && tcol == 0) {
            s_src[row] = ps; s_dst[row] = pd;
            z2[row] = make_float2(z0, z1);
        }
    }
}

// ---------------- last-layer agg + pool: 2 nodes/wave x 4 pairs, register g-accumulation ----------------

__global__ __launch_bounds__(256) void k_pool2(
    const float2* __restrict__ z2, const int* __restrict__ col,
    const int* __restrict__ rowptr, const float* __restrict__ s_src_in,
    const float* __restrict__ s_dst_in, const int* __restrict__ batch,
    float* __restrict__ pool_acc)
{
    int t = threadIdx.x;
    int wave = t >> 6, lane = t & 63;
    int h = lane >> 5, hl = lane & 31;
    int base0 = blockIdx.x * 32 + wave * 8;
    if (base0 >= N_NODES) return;
    float* rep = pool_acc + ((blockIdx.x * 4 + wave) & (NREP - 1)) * REP_STRIDE;

    int gcur = -1;
    float acc0 = 0.f, acc1 = 0.f;

#pragma unroll
    for (int i = 0; i < 4; ++i) {
        int node = base0 + 2 * i + h;
        bool valid = (node < N_NODES);
        int row = 0, end = 0;
        if (valid) { row = rowptr[node]; end = rowptr[node + 1]; }
        int deg = end - row;
        int degO = __shfl_xor(deg, 32);
        bool fast = (deg <= 32) && (degO <= 32);
        float r0 = 0.f, r1 = 0.f;

        if (fast) {
            float sdi = valid ? s_dst_in[node] : 0.f;
            float p = 0.f;
            float2 zv = make_float2(0.f, 0.f);
            if (hl < deg) {
                int c = col[row + hl];
                float ee = s_src_in[c] + sdi;
                ee = (ee >= 0.f) ? ee : NEG_SLOPE * ee;
                p = __expf(ee);
                zv = z2[c];
            }
            float n0 = p * zv.x, n1 = p * zv.y, dn = p;
#pragma unroll
            for (int off = 16; off >= 1; off >>= 1) {
                n0 += __shfl_xor(n0, off);
                n1 += __shfl_xor(n1, off);
                dn += __shfl_xor(dn, off);
            }
            float inv = 1.f / dn;
            r0 = n0 * inv; r1 = n1 * inv;
        } else {
            float rr0[2], rr1[2];
#pragma unroll
            for (int s = 0; s < 2; ++s) {
                rr0[s] = rr1[s] = 0.f;
                int nd = base0 + 2 * i + s;
                if (nd >= N_NODES) continue;
                int r = rowptr[nd], e = rowptr[nd + 1];
                float sdi = s_dst_in[nd];
                float n0 = 0.f, n1 = 0.f, dn = 0.f;
                for (int j = r + lane; j < e; j += 64) {
                    int c = col[j];
                    float ee = s_src_in[c] + sdi;
                    ee = (ee >= 0.f) ? ee : NEG_SLOPE * ee;
                    float p = __expf(ee);
                    float2 zv = z2[c];
                    n0 = fmaf(p, zv.x, n0);
                    n1 = fmaf(p, zv.y, n1);
                    dn += p;
                }
#pragma unroll
                for (int off = 32; off >= 1; off >>= 1) {
                    n0 += __shfl_xor(n0, off);
                    n1 += __shfl_xor(n1, off);
                    dn += __shfl_xor(dn, off);
                }
                float inv = 1.f / dn;
                rr0[s] = n0 * inv; rr1[s] = n1 * inv;
            }
            r0 = rr0[h]; r1 = rr1[h];
        }

        if (hl == 0 && valid) {
            int g = batch[node];
            if (g != gcur) {
                if (gcur >= 0) {
                    atomicAdd(&rep[gcur * 2], acc0);
                    atomicAdd(&rep[gcur * 2 + 1], acc1);
                }
                gcur = g; acc0 = r0; acc1 = r1;
            } else {
                acc0 += r0; acc1 += r1;
            }
        }
    }
    if (hl == 0 && gcur >= 0) {
        atomicAdd(&rep[gcur * 2], acc0);
        atomicAdd(&rep[gcur * 2 + 1], acc1);
    }
}

// ---------------- head: reduce replicas, divide by count, add consts ----------------

__device__ __forceinline__ int lower_bound_dev(const int* __restrict__ a, int n, int v) {
    int lo = 0, hi = n;
    while (lo < hi) {
        int mid = (lo + hi) >> 1;
        if (a[mid] < v) lo = mid + 1; else hi = mid;
    }
    return lo;
}

__global__ void k_head(const float* __restrict__ pool_acc,
                       const int* __restrict__ batch,
                       const float* __restrict__ b_out,
                       const float* __restrict__ sparams,
                       float* __restrict__ out)
{
    int t = threadIdx.x;
    if (t < 2 * N_GRAPHS) {
        float s = 0.f;
#pragma unroll 8
        for (int r = 0; r < NREP; ++r) s += pool_acc[r * REP_STRIDE + t];
        int g = t >> 1, c = t & 1;
        int start = lower_bound_dev(batch, N_NODES, g);
        int end = lower_bound_dev(batch, N_NODES, g + 1);
        float cnt = fmaxf((float)(end - start), 1.f);
        out[t] = s / cnt + sparams[4 + c] + b_out[c];
    }
}

// ---------------- launch ----------------

extern "C" void kernel_launch(void* const* d_in, const int* in_sizes, int n_in,
                              void* d_out, int out_size, void* d_ws, size_t ws_size,
                              hipStream_t stream) {
    const int*   x       = (const int*)d_in[0];
    const int*   edge    = (const int*)d_in[1];   // [2][E]
    const int*   batch   = (const int*)d_in[2];
    const float* embed   = (const float*)d_in[3];
    const float* Ws      = (const float*)d_in[4];
    const float* a_srcs  = (const float*)d_in[5];
    const float* a_dsts  = (const float*)d_in[6];
    const float* biases  = (const float*)d_in[7];
    const float* W_out   = (const float*)d_in[8];
    const float* b_out   = (const float*)d_in[9];
    float* out = (float*)d_out;

    char* ws = (char*)d_ws;
    size_t off = 0;
    auto alloc = [&](size_t bytes) -> void* {
        void* p = ws + off;
        off += (bytes + 255) & ~(size_t)255;
        return p;
    };
    unsigned short* hout  = (unsigned short*)alloc((size_t)N_NODES * 64 * sizeof(unsigned short));
    float2* z2      = (float2*)alloc((size_t)N_NODES * sizeof(float2));
    float* s_src0   = (float*)alloc((size_t)N_NODES * sizeof(float));
    float* s_dst0   = (float*)alloc((size_t)N_NODES * sizeof(float));
    unsigned short* cidx = (unsigned short*)alloc((size_t)N_NODES * sizeof(unsigned short));
    int*   rowptr   = (int*)alloc((size_t)(N_NODES + 1) * sizeof(int));
    int*   colA     = (int*)alloc((size_t)ETOT * sizeof(int));
    int*   blockcnt = (int*)alloc((size_t)PAIR_BLOCKS * NB * sizeof(int));
    int*   btot     = (int*)alloc((size_t)NB * sizeof(int));
    float* pool_acc = (float*)alloc((size_t)(NREP * REP_STRIDE) * sizeof(float));
    unsigned* xb    = (unsigned*)alloc((size_t)3232 * sizeof(unsigned));
    unsigned char* Tq8 = (unsigned char*)alloc((size_t)NLVL * 64);
    float* Tscl     = (float*)alloc((size_t)NLVL * sizeof(float));
    float* Ts1s     = (float*)alloc((size_t)NLVL * sizeof(float));
    float* Ts1d     = (float*)alloc((size_t)NLVL * sizeof(float));
    float* sparams  = (float*)alloc((size_t)8 * sizeof(float));
    int*   pairs    = (int*)alloc((size_t)N_EDGES * sizeof(int));  // dead after CSR build

    const int* e0 = edge;
    const int* e1 = edge + N_EDGES;

    // fused prep: bucket counts | layer-1 table | x bitmask
    k_prep<<<PAIR_BLOCKS + TBL_BLOCKS + XBIT_BLOCKS, 256, 0, stream>>>(
        e1, x, embed, Ws, biases, a_srcs, a_dsts, W_out,
        blockcnt, pool_acc, xb, Tq8, Tscl, Ts1s, Ts1d, sparams);
    k_scan_bases<<<NB, 64, 0, stream>>>(blockcnt, btot);
    k_pair_scatter<<<PAIR_BLOCKS, 256, 0, stream>>>(e0, e1, xb, btot, blockcnt, pairs);
    k_csr_bucket<<<NB, 512, 0, stream>>>(pairs, btot, x, sparams, rowptr, colA, cidx);

    // layer 1: table-based aggregation (2 nodes/wave) -> bf16 hout
    k_agg1<<<(N_NODES + 7) / 8, 256, 0, stream>>>(
        Tq8, Tscl, Ts1s, Ts1d, cidx, colA, rowptr, biases + 64, hout);
    // layer 2: GEMM -> scores + z, then 8-B-gather pool
    k_gemm2<<<(N_NODES + 63) / 64, 256, 0, stream>>>(
        (const unsigned*)hout, Ws + 8192, a_srcs + 128, a_dsts + 128, W_out,
        z2, s_src0, s_dst0);
    k_pool2<<<(N_NODES + 31) / 32, 256, 0, stream>>>(
        z2, colA, rowptr, s_src0, s_dst0, batch, pool_acc);
    k_head<<<1, 256, 0, stream>>>(pool_acc, batch, b_out, sparams, out);
}